// Round 1
// baseline (22028.876 us; speedup 1.0000x reference)
//
#include <hip/hip_runtime.h>
#include <hip/hip_cooperative_groups.h>

namespace cg = cooperative_groups;

#define BATCH  64
#define TT     512
#define IDIM   64
#define HDIM   512
#define NAHEAD 24
#define HB     (HDIM * BATCH)

// ---- encoder_coop LDS layout (floats) ----
#define ENC_WIH0    (8 * IDIM)                 // 512
#define ENC_WROW    (8 * HDIM)                 // 4096 (per weight matrix)
#define ENC_SCRATCH (8 * 64 * 17 + 8 * 64)     // 9216
#define ENC_SMEM_FLOATS (ENC_WIH0 + 3 * ENC_WROW + ENC_SCRATCH + 16)
#define ENC_SMEM_BYTES  (ENC_SMEM_FLOATS * 4)  // 88128 B < 160 KiB

__device__ __forceinline__ float4 ld4(const float* p) {
  return *reinterpret_cast<const float4*>(p);
}
__device__ __forceinline__ float sigm(float x) { return 1.0f / (1.0f + expf(-x)); }

// ---------------------------------------------------------------------------
// Persistent-weight LSTM cell: weights already staged in LDS ([8][DIN0] and
// [8][512], d = gate*2+col), c-state in registers of threads tid<128.
// 1024 threads: (b = tid&63, ks = tid>>6). Weight reads are wave-uniform LDS
// broadcasts (free); inputs are coalesced global loads. Reduce via LDS
// [8][64][17]. Ends with __syncthreads (scratch reusable).
// ---------------------------------------------------------------------------
template <int DIN0>
__device__ __forceinline__ void cell_lds(
    int j0,
    const float* __restrict__ in0,             // [DIN0][B] global
    const float* __restrict__ h_in,            // [512][B] global
    const float* wi,                           // LDS [8][DIN0]
    const float* wh,                           // LDS [8][512]
    const float* bias,                         // LDS [8] (b_ih[r]+b_hh[r])
    float& creg,                               // c-state (valid for tid<128)
    float* __restrict__ h_out,                 // [512][B] global
    float* sm)                                 // LDS scratch (ENC_SCRATCH)
{
  const int tid = threadIdx.x;
  const int b  = tid & 63;
  const int ks = tid >> 6;                 // 0..15, uniform per wave
  constexpr int K  = DIN0 + HDIM;
  constexpr int KS = K / 16;               // 36 (L0) / 64 (L1), %4 == 0
  const int k0 = ks * KS, k1 = k0 + KS;
  const int a0 = (k0 < DIN0) ? k0 : DIN0;
  const int a1 = (k1 < DIN0) ? k1 : DIN0;
  const int c0 = (k0 > DIN0) ? k0 - DIN0 : 0;
  const int c1 = (k1 > DIN0) ? k1 - DIN0 : 0;

  float acc[8] = {0.f, 0.f, 0.f, 0.f, 0.f, 0.f, 0.f, 0.f};

#pragma unroll 2
  for (int k = a0; k < a1; k += 4) {       // input-projection slice
    float x0 = in0[(k + 0) * BATCH + b];
    float x1 = in0[(k + 1) * BATCH + b];
    float x2 = in0[(k + 2) * BATCH + b];
    float x3 = in0[(k + 3) * BATCH + b];
#pragma unroll
    for (int d = 0; d < 8; ++d) {
      float4 w = ld4(wi + d * DIN0 + k);   // LDS broadcast, 16B aligned
      acc[d] += x0 * w.x + x1 * w.y + x2 * w.z + x3 * w.w;
    }
  }
#pragma unroll 2
  for (int k = c0; k < c1; k += 4) {       // recurrent slice
    float h0 = h_in[(k + 0) * BATCH + b];
    float h1 = h_in[(k + 1) * BATCH + b];
    float h2 = h_in[(k + 2) * BATCH + b];
    float h3 = h_in[(k + 3) * BATCH + b];
#pragma unroll
    for (int d = 0; d < 8; ++d) {
      float4 w = ld4(wh + d * HDIM + k);
      acc[d] += h0 * w.x + h1 * w.y + h2 * w.z + h3 * w.w;
    }
  }

  float* gl = sm + 8 * 64 * 17;
#pragma unroll
  for (int d = 0; d < 8; ++d) sm[(d * 64 + b) * 17 + ks] = acc[d];
  __syncthreads();

  if (tid < 512) {                          // reduce 16 partials per dot
    const int dd = tid >> 6, bb = tid & 63;
    float s = 0.f;
#pragma unroll
    for (int i = 0; i < 16; ++i) s += sm[(dd * 64 + bb) * 17 + i];
    gl[dd * 64 + bb] = s + bias[dd];
  }
  __syncthreads();

  if (tid < 128) {                          // cell update (col, b), c in reg
    const int bb = tid & 63, cl = tid >> 6;
    float gi = gl[(0 + cl) * 64 + bb];      // gate order i,f,g,o
    float gf = gl[(2 + cl) * 64 + bb];
    float gg = gl[(4 + cl) * 64 + bb];
    float go = gl[(6 + cl) * 64 + bb];
    float cn = sigm(gf) * creg + sigm(gi) * tanhf(gg);
    float hn = sigm(go) * tanhf(cn);
    creg = cn;
    h_out[(size_t)(j0 + cl) * BATCH + bb] = hn;
  }
  __syncthreads();   // scratch safe for reuse
}

// ---------------------------------------------------------------------------
// Whole encoder in ONE cooperative kernel: 256 WGs x 1024 (1 WG/CU).
// Per WG: stage its 8 weight rows of all 4 matrices into LDS once (50 KB),
// hold c0/c1 in registers, loop t = 0..512 with grid.sync() per step.
// Pipelined as before: L0 at t, L1 at t-1; no same-step cross-WG dependency.
// ---------------------------------------------------------------------------
__global__ __launch_bounds__(1024, 1)
void encoder_coop(const float* __restrict__ xT,
                  const float* __restrict__ w_ih0, const float* __restrict__ w_hh0,
                  const float* __restrict__ b_ih0, const float* __restrict__ b_hh0,
                  const float* __restrict__ w_ih1, const float* __restrict__ w_hh1,
                  const float* __restrict__ b_ih1, const float* __restrict__ b_hh1,
                  float* __restrict__ seq0,        // [T+1][H][B], slot0 zero
                  float* __restrict__ enc,         // [T+1][H][B], slot0 zero
                  float* __restrict__ cst1)        // [H][B] final L1 c-state
{
  extern __shared__ float smem[];
  float* wih0    = smem;                       // [8][64]
  float* whh0    = wih0 + ENC_WIH0;            // [8][512]
  float* wih1    = whh0 + ENC_WROW;            // [8][512]
  float* whh1    = wih1 + ENC_WROW;            // [8][512]
  float* scratch = whh1 + ENC_WROW;            // ENC_SCRATCH
  float* bias0   = scratch + ENC_SCRATCH;      // [8]
  float* bias1   = bias0 + 8;                  // [8]

  const int tid = threadIdx.x;
  const int j0  = blockIdx.x * 2;

  // ---- one-time weight staging: rows r(d) = (d>>1)*HDIM + j0 + (d&1) ----
  for (int idx = tid; idx < ENC_WIH0; idx += 1024) {
    int d = idx >> 6, k = idx & 63;
    size_t r = (size_t)((d >> 1) * HDIM + j0 + (d & 1));
    wih0[idx] = w_ih0[r * IDIM + k];
  }
  for (int idx = tid; idx < ENC_WROW; idx += 1024) {
    int d = idx >> 9, k = idx & 511;
    size_t r = (size_t)((d >> 1) * HDIM + j0 + (d & 1));
    whh0[idx] = w_hh0[r * HDIM + k];
    wih1[idx] = w_ih1[r * HDIM + k];
    whh1[idx] = w_hh1[r * HDIM + k];
  }
  if (tid < 8) {
    size_t r = (size_t)((tid >> 1) * HDIM + j0 + (tid & 1));
    bias0[tid] = b_ih0[r] + b_hh0[r];
    bias1[tid] = b_ih1[r] + b_hh1[r];
  }
  __syncthreads();

  float c0reg = 0.f, c1reg = 0.f;              // c-state (threads tid<128)
  cg::grid_group grid = cg::this_grid();

  for (int t = 0; t <= TT; ++t) {
    if (t < TT)
      cell_lds<IDIM>(j0, xT + (size_t)t * IDIM * BATCH,
                     seq0 + (size_t)t * HB,
                     wih0, whh0, bias0, c0reg,
                     seq0 + (size_t)(t + 1) * HB, scratch);
    if (t >= 1)
      cell_lds<HDIM>(j0, seq0 + (size_t)t * HB,
                     enc + (size_t)(t - 1) * HB,
                     wih1, whh1, bias1, c1reg,
                     enc + (size_t)t * HB, scratch);
    if (t < TT) grid.sync();                   // uniform; skip after last step
  }

  if (tid < 128)                               // decoder continues this c
    cst1[(size_t)(j0 + (tid >> 6)) * BATCH + (tid & 63)] = c1reg;
}

// ---------------------------------------------------------------------------
// Original global-weight cell (kept for dec_gates + launch fallback).
// ---------------------------------------------------------------------------
template <int DIN0>
__device__ __forceinline__ void cell_tile2(
    int j0, const float* __restrict__ in0,
    const float* __restrict__ h_in,
    const float* __restrict__ w_ih,
    const float* __restrict__ w_hh,
    const float* __restrict__ b_ih, const float* __restrict__ b_hh,
    float* __restrict__ c_state,
    float* __restrict__ h_out,
    float* __restrict__ sm)
{
  const int tid = threadIdx.x;
  const int b  = tid & 63;
  const int ks = tid >> 6;
  constexpr int K  = DIN0 + HDIM;
  constexpr int KS = K / 16;
  const int k0 = ks * KS, k1 = k0 + KS;
  const int a0 = (k0 < DIN0) ? k0 : DIN0;
  const int a1 = (k1 < DIN0) ? k1 : DIN0;
  const int c0 = (k0 > DIN0) ? k0 - DIN0 : 0;
  const int c1 = (k1 > DIN0) ? k1 - DIN0 : 0;

  const float* wi = w_ih + (size_t)j0 * DIN0;
  const float* wh = w_hh + (size_t)j0 * HDIM;

  float acc[8] = {0.f, 0.f, 0.f, 0.f, 0.f, 0.f, 0.f, 0.f};

#pragma unroll 2
  for (int k = a0; k < a1; k += 4) {
    float x0 = in0[(k + 0) * BATCH + b];
    float x1 = in0[(k + 1) * BATCH + b];
    float x2 = in0[(k + 2) * BATCH + b];
    float x3 = in0[(k + 3) * BATCH + b];
#pragma unroll
    for (int d = 0; d < 8; ++d) {
      float4 w = ld4(wi + (size_t)((d >> 1) * HDIM + (d & 1)) * DIN0 + k);
      acc[d] += x0 * w.x + x1 * w.y + x2 * w.z + x3 * w.w;
    }
  }
#pragma unroll 2
  for (int k = c0; k < c1; k += 4) {
    float h0 = h_in[(k + 0) * BATCH + b];
    float h1 = h_in[(k + 1) * BATCH + b];
    float h2 = h_in[(k + 2) * BATCH + b];
    float h3 = h_in[(k + 3) * BATCH + b];
#pragma unroll
    for (int d = 0; d < 8; ++d) {
      float4 w = ld4(wh + (size_t)((d >> 1) * HDIM + (d & 1)) * HDIM + k);
      acc[d] += h0 * w.x + h1 * w.y + h2 * w.z + h3 * w.w;
    }
  }

  float* gl = sm + 8 * 64 * 17;
#pragma unroll
  for (int d = 0; d < 8; ++d) sm[(d * 64 + b) * 17 + ks] = acc[d];
  __syncthreads();

  if (tid < 512) {
    const int dd = tid >> 6, bb = tid & 63;
    float s = 0.f;
#pragma unroll
    for (int i = 0; i < 16; ++i) s += sm[(dd * 64 + bb) * 17 + i];
    const int r = (dd >> 1) * HDIM + j0 + (dd & 1);
    gl[dd * 64 + bb] = s + b_ih[r] + b_hh[r];
  }
  __syncthreads();

  if (tid < 128) {
    const int bb = tid & 63, cl = tid >> 6;
    const int jc = j0 + cl;
    float gi = gl[(0 + cl) * 64 + bb];
    float gf = gl[(2 + cl) * 64 + bb];
    float gg = gl[(4 + cl) * 64 + bb];
    float go = gl[(6 + cl) * 64 + bb];
    float cold = c_state[(size_t)jc * BATCH + bb];
    float cn = sigm(gf) * cold + sigm(gi) * tanhf(gg);
    float hn = sigm(go) * tanhf(cn);
    c_state[(size_t)jc * BATCH + bb] = cn;
    h_out[(size_t)jc * BATCH + bb] = hn;
  }
  __syncthreads();
}

// Fallback per-step kernel (only used if cooperative launch fails).
__global__ __launch_bounds__(1024, 1)
void lstm_step(int t,
               const float* __restrict__ xT,
               const float* __restrict__ w_ih0, const float* __restrict__ w_hh0,
               const float* __restrict__ b_ih0, const float* __restrict__ b_hh0,
               const float* __restrict__ w_ih1, const float* __restrict__ w_hh1,
               const float* __restrict__ b_ih1, const float* __restrict__ b_hh1,
               float* __restrict__ seq0, float* __restrict__ enc,
               float* __restrict__ cst0, float* __restrict__ cst1)
{
  __shared__ float sm[8 * 64 * 17 + 8 * 64];
  const int j0 = blockIdx.x * 2;
  if (t < TT)
    cell_tile2<IDIM>(j0, xT + (size_t)t * IDIM * BATCH,
                     seq0 + (size_t)t * HB,
                     w_ih0, w_hh0, b_ih0, b_hh0,
                     cst0, seq0 + (size_t)(t + 1) * HB, sm);
  if (t >= 1)
    cell_tile2<HDIM>(j0, seq0 + (size_t)t * HB,
                     enc + (size_t)(t - 1) * HB,
                     w_ih1, w_hh1, b_ih1, b_hh1,
                     cst1, enc + (size_t)t * HB, sm);
}

// ---------------------------------------------------------------------------
__global__ __launch_bounds__(1024, 1)
void dec_gates(const float* __restrict__ xi, const float* __restrict__ h_cur,
               const float* __restrict__ w_ih, const float* __restrict__ w_hh,
               const float* __restrict__ b_ih, const float* __restrict__ b_hh,
               float* __restrict__ cst, float* __restrict__ h_out)
{
  __shared__ float sm[8 * 64 * 17 + 8 * 64];
  cell_tile2<HDIM>(blockIdx.x * 2, xi, h_cur, w_ih, w_hh, b_ih, b_hh,
                   cst, h_out, sm);
}

// ---------------------------------------------------------------------------
__global__ __launch_bounds__(512, 2)
void attn_scores(const float* __restrict__ enc,
                 const float* __restrict__ h_cur,
                 float* __restrict__ scores)
{
  __shared__ float red[2][8][64];
  const int tid = threadIdx.x;
  const int b  = tid & 63;
  const int ks = tid >> 6;
  const int t0 = blockIdx.x * 2;
  const float* e0 = enc + (size_t)(t0 + 1) * HB + ks * 64 * BATCH;
  const float* e1 = e0 + HB;
  const float* hr = h_cur + ks * 64 * BATCH;
  float a0 = 0.f, a1 = 0.f;
#pragma unroll 4
  for (int k = 0; k < 64; ++k) {
    float hv = hr[k * BATCH + b];
    a0 += hv * e0[k * BATCH + b];
    a1 += hv * e1[k * BATCH + b];
  }
  red[0][ks][b] = a0;
  red[1][ks][b] = a1;
  __syncthreads();
  if (tid < 128) {
    int tl = tid >> 6;
    float s = 0.f;
#pragma unroll
    for (int i = 0; i < 8; ++i) s += red[tl][i][b];
    scores[(size_t)(t0 + tl) * BATCH + b] = s;
  }
}

// ---------------------------------------------------------------------------
__global__ __launch_bounds__(512, 2)
void attn_ctx(const float* __restrict__ enc,
              const float* __restrict__ scores,
              const float* __restrict__ h_cur,
              const float* __restrict__ w_fc, const float* __restrict__ b_fc,
              float* __restrict__ xi,
              float* __restrict__ out,
              int s)
{
  __shared__ float red[8][2][64];
  __shared__ float mz[2][64];
  __shared__ float ctxv[2][64];
  const int tid = threadIdx.x;
  const int b  = tid & 63;
  const int ts = tid >> 6;
  const int hc0 = blockIdx.x * 2;

  float m = -1e30f;
  for (int t = ts * 64; t < ts * 64 + 64; ++t)
    m = fmaxf(m, scores[(size_t)t * BATCH + b]);
  red[ts][0][b] = m;
  __syncthreads();
  if (tid < 64) {
    float mm = red[0][0][b];
#pragma unroll
    for (int i = 1; i < 8; ++i) mm = fmaxf(mm, red[i][0][b]);
    mz[0][b] = mm;
  }
  __syncthreads();
  m = mz[0][b];
  float z = 0.f;
  for (int t = ts * 64; t < ts * 64 + 64; ++t)
    z += expf(scores[(size_t)t * BATCH + b] - m);
  red[ts][1][b] = z;
  __syncthreads();
  if (tid < 64) {
    float zz = 0.f;
#pragma unroll
    for (int i = 0; i < 8; ++i) zz += red[i][1][b];
    mz[1][b] = 1.f / zz;
  }
  __syncthreads();
  const float rZ = mz[1][b];

  float a0 = 0.f, a1 = 0.f;
  const float* eb = enc + HB + (size_t)hc0 * BATCH + b;
  for (int t = ts * 64; t < ts * 64 + 64; ++t) {
    float p = expf(scores[(size_t)t * BATCH + b] - m) * rZ;
    a0 += p * eb[(size_t)t * HB];
    a1 += p * eb[(size_t)t * HB + BATCH];
  }
  __syncthreads();
  red[ts][0][b] = a0;
  red[ts][1][b] = a1;
  __syncthreads();
  if (tid < 128) {
    int cl = tid >> 6;
    float c = 0.f;
#pragma unroll
    for (int i = 0; i < 8; ++i) c += red[i][cl][b];
    ctxv[cl][b] = c;
  }

  float p0 = 0.f, p1 = 0.f;
  if (s >= 1) {
    const float* w0 = w_fc + (size_t)hc0 * HDIM + ts * 64;
    const float* w1 = w0 + HDIM;
    const float* hr = h_cur + ts * 64 * BATCH;
#pragma unroll 2
    for (int k = 0; k < 64; k += 4) {
      float4 wa = ld4(w0 + k), wb = ld4(w1 + k);
      float h0 = hr[(k + 0) * BATCH + b], h1 = hr[(k + 1) * BATCH + b];
      float h2 = hr[(k + 2) * BATCH + b], h3 = hr[(k + 3) * BATCH + b];
      p0 += wa.x * h0 + wa.y * h1 + wa.z * h2 + wa.w * h3;
      p1 += wb.x * h0 + wb.y * h1 + wb.z * h2 + wb.w * h3;
    }
  }
  __syncthreads();
  red[ts][0][b] = p0;
  red[ts][1][b] = p1;
  __syncthreads();
  if (tid < 128) {
    int cl = tid >> 6;
    int cc = hc0 + cl;
    float pred = 0.f;
    if (s >= 1) {
#pragma unroll
      for (int i = 0; i < 8; ++i) pred += red[i][cl][b];
      pred += b_fc[cc];
      out[((size_t)b * NAHEAD + (s - 1)) * HDIM + cc] = pred;
    }
    xi[(size_t)cc * BATCH + b] = ctxv[cl][b] + pred;
  }
}

// ---------------------------------------------------------------------------
__global__ __launch_bounds__(512, 2)
void fc_out(const float* __restrict__ h, const float* __restrict__ w_fc,
            const float* __restrict__ b_fc, float* __restrict__ out, int srow)
{
  __shared__ float red[8][2][64];
  const int tid = threadIdx.x;
  const int b  = tid & 63;
  const int ks = tid >> 6;
  const int cc0 = blockIdx.x * 2;
  const float* w0 = w_fc + (size_t)cc0 * HDIM + ks * 64;
  const float* w1 = w0 + HDIM;
  const float* hr = h + ks * 64 * BATCH;
  float p0 = 0.f, p1 = 0.f;
#pragma unroll 2
  for (int k = 0; k < 64; k += 4) {
    float4 wa = ld4(w0 + k), wb = ld4(w1 + k);
    float h0 = hr[(k + 0) * BATCH + b], h1 = hr[(k + 1) * BATCH + b];
    float h2 = hr[(k + 2) * BATCH + b], h3 = hr[(k + 3) * BATCH + b];
    p0 += wa.x * h0 + wa.y * h1 + wa.z * h2 + wa.w * h3;
    p1 += wb.x * h0 + wb.y * h1 + wb.z * h2 + wb.w * h3;
  }
  red[ks][0][b] = p0;
  red[ks][1][b] = p1;
  __syncthreads();
  if (tid < 128) {
    int cl = tid >> 6;
    int cc = cc0 + cl;
    float p = 0.f;
#pragma unroll
    for (int i = 0; i < 8; ++i) p += red[i][cl][b];
    out[((size_t)b * NAHEAD + srow) * HDIM + cc] = p + b_fc[cc];
  }
}

// ---------------------------------------------------------------------------
__global__ __launch_bounds__(256)
void transpose_x(const float* __restrict__ x, float* __restrict__ xT)
{
  __shared__ float tile[64][65];
  const int t = blockIdx.x;
  const int lane = threadIdx.x & 63;
  const int w    = threadIdx.x >> 6;
#pragma unroll
  for (int ii = 0; ii < 16; ++ii) {
    int b = w * 16 + ii;
    tile[b][lane] = x[((size_t)b * TT + t) * IDIM + lane];
  }
  __syncthreads();
#pragma unroll
  for (int ii = 0; ii < 16; ++ii) {
    int i = w * 16 + ii;
    xT[((size_t)t * IDIM + i) * BATCH + lane] = tile[lane][i];
  }
}

// ---------------------------------------------------------------------------
extern "C" void kernel_launch(void* const* d_in, const int* in_sizes, int n_in,
                              void* d_out, int out_size, void* d_ws, size_t ws_size,
                              hipStream_t stream) {
  const float* x     = (const float*)d_in[0];
  const float* w_ih0 = (const float*)d_in[1];
  const float* w_hh0 = (const float*)d_in[2];
  const float* b_ih0 = (const float*)d_in[3];
  const float* b_hh0 = (const float*)d_in[4];
  const float* w_ih1 = (const float*)d_in[5];
  const float* w_hh1 = (const float*)d_in[6];
  const float* b_ih1 = (const float*)d_in[7];
  const float* b_hh1 = (const float*)d_in[8];
  const float* w_ihd = (const float*)d_in[9];
  const float* w_hhd = (const float*)d_in[10];
  const float* b_ihd = (const float*)d_in[11];
  const float* b_hhd = (const float*)d_in[12];
  const float* w_fc  = (const float*)d_in[13];
  const float* b_fc  = (const float*)d_in[14];
  float* out = (float*)d_out;

  char* ws = (char*)d_ws;
  size_t off = 0;
  auto alloc = [&](size_t bytes) -> void* {
    void* p = ws + off;
    off += (bytes + 255) & ~(size_t)255;
    return p;
  };

  float* cst0 = (float*)alloc((size_t)HB * 4);            // zero (fallback)
  float* cst1 = (float*)alloc((size_t)HB * 4);            // final L1 c-state
  float* seq0 = (float*)alloc((size_t)(TT + 1) * HB * 4); // slot0 zero
  float* enc  = (float*)alloc((size_t)(TT + 1) * HB * 4); // slot0 zero
  float* xT   = (float*)alloc((size_t)TT * IDIM * BATCH * 4);
  float* scores = (float*)alloc((size_t)TT * BATCH * 4);
  float* xi     = (float*)alloc((size_t)HB * 4);
  float* hdec   = (float*)alloc((size_t)2 * HB * 4);
  (void)ws_size; (void)in_sizes; (void)n_in; (void)out_size;

  hipMemsetAsync(cst0, 0, (size_t)HB * 4 * 2, stream);    // cst0+cst1
  hipMemsetAsync(seq0, 0, (size_t)HB * 4, stream);
  hipMemsetAsync(enc,  0, (size_t)HB * 4, stream);

  transpose_x<<<TT, 256, 0, stream>>>(x, xT);

  // ---- encoder: ONE cooperative kernel, grid.sync() per timestep ----
  static bool attr_set = false;
  if (!attr_set) {
    hipFuncSetAttribute(reinterpret_cast<const void*>(encoder_coop),
                        hipFuncAttributeMaxDynamicSharedMemorySize,
                        ENC_SMEM_BYTES);
    attr_set = true;
  }
  void* args[] = {
    (void*)&xT,
    (void*)&w_ih0, (void*)&w_hh0, (void*)&b_ih0, (void*)&b_hh0,
    (void*)&w_ih1, (void*)&w_hh1, (void*)&b_ih1, (void*)&b_hh1,
    (void*)&seq0, (void*)&enc, (void*)&cst1
  };
  hipError_t cerr = hipLaunchCooperativeKernel(
      reinterpret_cast<void*>(encoder_coop), dim3(256), dim3(1024),
      args, (unsigned)ENC_SMEM_BYTES, stream);
  if (cerr != hipSuccess) {
    // fallback: original 513 pipelined launches
    for (int t = 0; t <= TT; ++t) {
      lstm_step<<<256, 1024, 0, stream>>>(
          t, xT, w_ih0, w_hh0, b_ih0, b_hh0,
          w_ih1, w_hh1, b_ih1, b_hh1, seq0, enc, cst0, cst1);
    }
  }

  // ---- decoder (unchanged) ----
  const float* h_cur = enc + (size_t)TT * HB;
  for (int s = 0; s < NAHEAD; ++s) {
    attn_scores<<<256, 512, 0, stream>>>(enc, h_cur, scores);
    attn_ctx<<<256, 512, 0, stream>>>(enc, scores, h_cur, w_fc, b_fc,
                                      xi, out, s);
    float* h_nxt = hdec + (size_t)(s & 1) * HB;
    dec_gates<<<256, 1024, 0, stream>>>(xi, h_cur, w_ihd, w_hhd,
                                        b_ihd, b_hhd, cst1, h_nxt);
    h_cur = h_nxt;
  }
  fc_out<<<256, 512, 0, stream>>>(h_cur, w_fc, b_fc, out, NAHEAD - 1);
}

// Round 2
// 10208.235 us; speedup vs baseline: 2.1580x; 2.1580x over previous
//
#include <hip/hip_runtime.h>
#include <hip/hip_cooperative_groups.h>

namespace cg = cooperative_groups;

#define BATCH  64
#define TT     512
#define IDIM   64
#define HDIM   512
#define NAHEAD 24
#define HB     (HDIM * BATCH)

// ---- encoder_coop LDS layout (floats) ----
#define ENC_WIH0    (8 * IDIM)                 // 512
#define ENC_WROW    (8 * HDIM)                 // 4096 (per weight matrix)
#define ENC_SCRATCH (8 * 64 * 17 + 8 * 64)     // 9216
#define ENC_SMEM_FLOATS (ENC_WIH0 + 3 * ENC_WROW + ENC_SCRATCH + 16)
#define ENC_SMEM_BYTES  (ENC_SMEM_FLOATS * 4)  // 88128 B < 160 KiB

__device__ __forceinline__ float4 ld4(const float* p) {
  return *reinterpret_cast<const float4*>(p);
}
__device__ __forceinline__ float sigm(float x) { return 1.0f / (1.0f + expf(-x)); }

// ---------------------------------------------------------------------------
// Flush-free grid barrier. Monotonic counter at agent scope, RELAXED ordering
// (no buffer_wbl2 / buffer_inv — cg::grid.sync's L2 flush per step was the
// round-1 regression). Safe here because every cross-WG datum (seq0/enc slot)
// is written exactly once (sc1 write-through via agent-relaxed atomic store)
// and only read at the following step — no stale L2 copy can exist.
// All threads drain their own vmcnt BEFORE the signal so the tid<128 h-stores
// are at the coherence point when tid 0 increments the counter.
// ---------------------------------------------------------------------------
__device__ __forceinline__ void grid_barrier(unsigned* cnt, unsigned target) {
  asm volatile("s_waitcnt vmcnt(0)" ::: "memory");
  __syncthreads();
  if (threadIdx.x == 0) {
    __hip_atomic_fetch_add(cnt, 1u, __ATOMIC_RELAXED, __HIP_MEMORY_SCOPE_AGENT);
    while (__hip_atomic_load(cnt, __ATOMIC_RELAXED,
                             __HIP_MEMORY_SCOPE_AGENT) < target)
      __builtin_amdgcn_s_sleep(2);
  }
  __syncthreads();
  asm volatile("" ::: "memory");
}

// ---------------------------------------------------------------------------
// Persistent-weight LSTM cell: weights already staged in LDS ([8][DIN0] and
// [8][512], d = gate*2+col), c-state in registers of threads tid<128.
// 1024 threads: (b = tid&63, ks = tid>>6). Weight reads are wave-uniform LDS
// broadcasts; inputs are coalesced global loads. h-state stores go out with
// agent scope (sc1 write-through) so the next step's cross-XCD readers see
// them without any cache flush.
// ---------------------------------------------------------------------------
template <int DIN0>
__device__ __forceinline__ void cell_lds(
    int j0,
    const float* __restrict__ in0,             // [DIN0][B] global
    const float* __restrict__ h_in,            // [512][B] global
    const float* wi,                           // LDS [8][DIN0]
    const float* wh,                           // LDS [8][512]
    const float* bias,                         // LDS [8] (b_ih[r]+b_hh[r])
    float& creg,                               // c-state (valid for tid<128)
    float* __restrict__ h_out,                 // [512][B] global
    float* sm)                                 // LDS scratch (ENC_SCRATCH)
{
  const int tid = threadIdx.x;
  const int b  = tid & 63;
  const int ks = tid >> 6;                 // 0..15, uniform per wave
  constexpr int K  = DIN0 + HDIM;
  constexpr int KS = K / 16;               // 36 (L0) / 64 (L1), %4 == 0
  const int k0 = ks * KS, k1 = k0 + KS;
  const int a0 = (k0 < DIN0) ? k0 : DIN0;
  const int a1 = (k1 < DIN0) ? k1 : DIN0;
  const int c0 = (k0 > DIN0) ? k0 - DIN0 : 0;
  const int c1 = (k1 > DIN0) ? k1 - DIN0 : 0;

  float acc[8] = {0.f, 0.f, 0.f, 0.f, 0.f, 0.f, 0.f, 0.f};

#pragma unroll 2
  for (int k = a0; k < a1; k += 4) {       // input-projection slice
    float x0 = in0[(k + 0) * BATCH + b];
    float x1 = in0[(k + 1) * BATCH + b];
    float x2 = in0[(k + 2) * BATCH + b];
    float x3 = in0[(k + 3) * BATCH + b];
#pragma unroll
    for (int d = 0; d < 8; ++d) {
      float4 w = ld4(wi + d * DIN0 + k);   // LDS broadcast, 16B aligned
      acc[d] += x0 * w.x + x1 * w.y + x2 * w.z + x3 * w.w;
    }
  }
#pragma unroll 2
  for (int k = c0; k < c1; k += 4) {       // recurrent slice
    float h0 = h_in[(k + 0) * BATCH + b];
    float h1 = h_in[(k + 1) * BATCH + b];
    float h2 = h_in[(k + 2) * BATCH + b];
    float h3 = h_in[(k + 3) * BATCH + b];
#pragma unroll
    for (int d = 0; d < 8; ++d) {
      float4 w = ld4(wh + d * HDIM + k);
      acc[d] += h0 * w.x + h1 * w.y + h2 * w.z + h3 * w.w;
    }
  }

  float* gl = sm + 8 * 64 * 17;
#pragma unroll
  for (int d = 0; d < 8; ++d) sm[(d * 64 + b) * 17 + ks] = acc[d];
  __syncthreads();

  if (tid < 512) {                          // reduce 16 partials per dot
    const int dd = tid >> 6, bb = tid & 63;
    float s = 0.f;
#pragma unroll
    for (int i = 0; i < 16; ++i) s += sm[(dd * 64 + bb) * 17 + i];
    gl[dd * 64 + bb] = s + bias[dd];
  }
  __syncthreads();

  if (tid < 128) {                          // cell update (col, b), c in reg
    const int bb = tid & 63, cl = tid >> 6;
    float gi = gl[(0 + cl) * 64 + bb];      // gate order i,f,g,o
    float gf = gl[(2 + cl) * 64 + bb];
    float gg = gl[(4 + cl) * 64 + bb];
    float go = gl[(6 + cl) * 64 + bb];
    float cn = sigm(gf) * creg + sigm(gi) * tanhf(gg);
    float hn = sigm(go) * tanhf(cn);
    creg = cn;
    // agent-scope write-through (sc1): visible device-wide after vmcnt drain
    __hip_atomic_store(&h_out[(size_t)(j0 + cl) * BATCH + bb], hn,
                       __ATOMIC_RELAXED, __HIP_MEMORY_SCOPE_AGENT);
  }
  __syncthreads();   // scratch safe for reuse
}

// ---------------------------------------------------------------------------
// Whole encoder in ONE cooperative kernel: 256 WGs x 1024 (1 WG/CU).
// Per WG: stage its 8 weight rows of all 4 matrices into LDS once (50 KB),
// hold c0/c1 in registers, loop t = 0..512 with a flush-free barrier per step.
// Pipelined: L0 at t, L1 at t-1; no same-step cross-WG dependency.
// ---------------------------------------------------------------------------
__global__ __launch_bounds__(1024, 1)
void encoder_coop(const float* __restrict__ xT,
                  const float* __restrict__ w_ih0, const float* __restrict__ w_hh0,
                  const float* __restrict__ b_ih0, const float* __restrict__ b_hh0,
                  const float* __restrict__ w_ih1, const float* __restrict__ w_hh1,
                  const float* __restrict__ b_ih1, const float* __restrict__ b_hh1,
                  float* __restrict__ seq0,        // [T+1][H][B], slot0 zero
                  float* __restrict__ enc,         // [T+1][H][B], slot0 zero
                  float* __restrict__ cst1,        // [H][B] final L1 c-state
                  unsigned* bar)                   // grid barrier counter (=0)
{
  extern __shared__ float smem[];
  float* wih0    = smem;                       // [8][64]
  float* whh0    = wih0 + ENC_WIH0;            // [8][512]
  float* wih1    = whh0 + ENC_WROW;            // [8][512]
  float* whh1    = wih1 + ENC_WROW;            // [8][512]
  float* scratch = whh1 + ENC_WROW;            // ENC_SCRATCH
  float* bias0   = scratch + ENC_SCRATCH;      // [8]
  float* bias1   = bias0 + 8;                  // [8]

  const int tid = threadIdx.x;
  const int j0  = blockIdx.x * 2;

  // ---- one-time weight staging: rows r(d) = (d>>1)*HDIM + j0 + (d&1) ----
  for (int idx = tid; idx < ENC_WIH0; idx += 1024) {
    int d = idx >> 6, k = idx & 63;
    size_t r = (size_t)((d >> 1) * HDIM + j0 + (d & 1));
    wih0[idx] = w_ih0[r * IDIM + k];
  }
  for (int idx = tid; idx < ENC_WROW; idx += 1024) {
    int d = idx >> 9, k = idx & 511;
    size_t r = (size_t)((d >> 1) * HDIM + j0 + (d & 1));
    whh0[idx] = w_hh0[r * HDIM + k];
    wih1[idx] = w_ih1[r * HDIM + k];
    whh1[idx] = w_hh1[r * HDIM + k];
  }
  if (tid < 8) {
    size_t r = (size_t)((tid >> 1) * HDIM + j0 + (tid & 1));
    bias0[tid] = b_ih0[r] + b_hh0[r];
    bias1[tid] = b_ih1[r] + b_hh1[r];
  }
  __syncthreads();

  float c0reg = 0.f, c1reg = 0.f;              // c-state (threads tid<128)

  for (int t = 0; t <= TT; ++t) {
    if (t < TT)
      cell_lds<IDIM>(j0, xT + (size_t)t * IDIM * BATCH,
                     seq0 + (size_t)t * HB,
                     wih0, whh0, bias0, c0reg,
                     seq0 + (size_t)(t + 1) * HB, scratch);
    if (t >= 1)
      cell_lds<HDIM>(j0, seq0 + (size_t)t * HB,
                     enc + (size_t)(t - 1) * HB,
                     wih1, whh1, bias1, c1reg,
                     enc + (size_t)t * HB, scratch);
    if (t < TT) grid_barrier(bar, 256u * (unsigned)(t + 1));
  }

  if (tid < 128)                               // decoder continues this c
    cst1[(size_t)(j0 + (tid >> 6)) * BATCH + (tid & 63)] = c1reg;
}

// ---------------------------------------------------------------------------
// Original global-weight cell (kept for dec_gates + launch fallback).
// ---------------------------------------------------------------------------
template <int DIN0>
__device__ __forceinline__ void cell_tile2(
    int j0, const float* __restrict__ in0,
    const float* __restrict__ h_in,
    const float* __restrict__ w_ih,
    const float* __restrict__ w_hh,
    const float* __restrict__ b_ih, const float* __restrict__ b_hh,
    float* __restrict__ c_state,
    float* __restrict__ h_out,
    float* __restrict__ sm)
{
  const int tid = threadIdx.x;
  const int b  = tid & 63;
  const int ks = tid >> 6;
  constexpr int K  = DIN0 + HDIM;
  constexpr int KS = K / 16;
  const int k0 = ks * KS, k1 = k0 + KS;
  const int a0 = (k0 < DIN0) ? k0 : DIN0;
  const int a1 = (k1 < DIN0) ? k1 : DIN0;
  const int c0 = (k0 > DIN0) ? k0 - DIN0 : 0;
  const int c1 = (k1 > DIN0) ? k1 - DIN0 : 0;

  const float* wi = w_ih + (size_t)j0 * DIN0;
  const float* wh = w_hh + (size_t)j0 * HDIM;

  float acc[8] = {0.f, 0.f, 0.f, 0.f, 0.f, 0.f, 0.f, 0.f};

#pragma unroll 2
  for (int k = a0; k < a1; k += 4) {
    float x0 = in0[(k + 0) * BATCH + b];
    float x1 = in0[(k + 1) * BATCH + b];
    float x2 = in0[(k + 2) * BATCH + b];
    float x3 = in0[(k + 3) * BATCH + b];
#pragma unroll
    for (int d = 0; d < 8; ++d) {
      float4 w = ld4(wi + (size_t)((d >> 1) * HDIM + (d & 1)) * DIN0 + k);
      acc[d] += x0 * w.x + x1 * w.y + x2 * w.z + x3 * w.w;
    }
  }
#pragma unroll 2
  for (int k = c0; k < c1; k += 4) {
    float h0 = h_in[(k + 0) * BATCH + b];
    float h1 = h_in[(k + 1) * BATCH + b];
    float h2 = h_in[(k + 2) * BATCH + b];
    float h3 = h_in[(k + 3) * BATCH + b];
#pragma unroll
    for (int d = 0; d < 8; ++d) {
      float4 w = ld4(wh + (size_t)((d >> 1) * HDIM + (d & 1)) * HDIM + k);
      acc[d] += h0 * w.x + h1 * w.y + h2 * w.z + h3 * w.w;
    }
  }

  float* gl = sm + 8 * 64 * 17;
#pragma unroll
  for (int d = 0; d < 8; ++d) sm[(d * 64 + b) * 17 + ks] = acc[d];
  __syncthreads();

  if (tid < 512) {
    const int dd = tid >> 6, bb = tid & 63;
    float s = 0.f;
#pragma unroll
    for (int i = 0; i < 16; ++i) s += sm[(dd * 64 + bb) * 17 + i];
    const int r = (dd >> 1) * HDIM + j0 + (dd & 1);
    gl[dd * 64 + bb] = s + b_ih[r] + b_hh[r];
  }
  __syncthreads();

  if (tid < 128) {
    const int bb = tid & 63, cl = tid >> 6;
    const int jc = j0 + cl;
    float gi = gl[(0 + cl) * 64 + bb];
    float gf = gl[(2 + cl) * 64 + bb];
    float gg = gl[(4 + cl) * 64 + bb];
    float go = gl[(6 + cl) * 64 + bb];
    float cold = c_state[(size_t)jc * BATCH + bb];
    float cn = sigm(gf) * cold + sigm(gi) * tanhf(gg);
    float hn = sigm(go) * tanhf(cn);
    c_state[(size_t)jc * BATCH + bb] = cn;
    h_out[(size_t)jc * BATCH + bb] = hn;
  }
  __syncthreads();
}

// Fallback per-step kernel (only used if cooperative launch fails).
__global__ __launch_bounds__(1024, 1)
void lstm_step(int t,
               const float* __restrict__ xT,
               const float* __restrict__ w_ih0, const float* __restrict__ w_hh0,
               const float* __restrict__ b_ih0, const float* __restrict__ b_hh0,
               const float* __restrict__ w_ih1, const float* __restrict__ w_hh1,
               const float* __restrict__ b_ih1, const float* __restrict__ b_hh1,
               float* __restrict__ seq0, float* __restrict__ enc,
               float* __restrict__ cst0, float* __restrict__ cst1)
{
  __shared__ float sm[8 * 64 * 17 + 8 * 64];
  const int j0 = blockIdx.x * 2;
  if (t < TT)
    cell_tile2<IDIM>(j0, xT + (size_t)t * IDIM * BATCH,
                     seq0 + (size_t)t * HB,
                     w_ih0, w_hh0, b_ih0, b_hh0,
                     cst0, seq0 + (size_t)(t + 1) * HB, sm);
  if (t >= 1)
    cell_tile2<HDIM>(j0, seq0 + (size_t)t * HB,
                     enc + (size_t)(t - 1) * HB,
                     w_ih1, w_hh1, b_ih1, b_hh1,
                     cst1, enc + (size_t)t * HB, sm);
}

// ---------------------------------------------------------------------------
__global__ __launch_bounds__(1024, 1)
void dec_gates(const float* __restrict__ xi, const float* __restrict__ h_cur,
               const float* __restrict__ w_ih, const float* __restrict__ w_hh,
               const float* __restrict__ b_ih, const float* __restrict__ b_hh,
               float* __restrict__ cst, float* __restrict__ h_out)
{
  __shared__ float sm[8 * 64 * 17 + 8 * 64];
  cell_tile2<HDIM>(blockIdx.x * 2, xi, h_cur, w_ih, w_hh, b_ih, b_hh,
                   cst, h_out, sm);
}

// ---------------------------------------------------------------------------
__global__ __launch_bounds__(512, 2)
void attn_scores(const float* __restrict__ enc,
                 const float* __restrict__ h_cur,
                 float* __restrict__ scores)
{
  __shared__ float red[2][8][64];
  const int tid = threadIdx.x;
  const int b  = tid & 63;
  const int ks = tid >> 6;
  const int t0 = blockIdx.x * 2;
  const float* e0 = enc + (size_t)(t0 + 1) * HB + ks * 64 * BATCH;
  const float* e1 = e0 + HB;
  const float* hr = h_cur + ks * 64 * BATCH;
  float a0 = 0.f, a1 = 0.f;
#pragma unroll 4
  for (int k = 0; k < 64; ++k) {
    float hv = hr[k * BATCH + b];
    a0 += hv * e0[k * BATCH + b];
    a1 += hv * e1[k * BATCH + b];
  }
  red[0][ks][b] = a0;
  red[1][ks][b] = a1;
  __syncthreads();
  if (tid < 128) {
    int tl = tid >> 6;
    float s = 0.f;
#pragma unroll
    for (int i = 0; i < 8; ++i) s += red[tl][i][b];
    scores[(size_t)(t0 + tl) * BATCH + b] = s;
  }
}

// ---------------------------------------------------------------------------
__global__ __launch_bounds__(512, 2)
void attn_ctx(const float* __restrict__ enc,
              const float* __restrict__ scores,
              const float* __restrict__ h_cur,
              const float* __restrict__ w_fc, const float* __restrict__ b_fc,
              float* __restrict__ xi,
              float* __restrict__ out,
              int s)
{
  __shared__ float red[8][2][64];
  __shared__ float mz[2][64];
  __shared__ float ctxv[2][64];
  const int tid = threadIdx.x;
  const int b  = tid & 63;
  const int ts = tid >> 6;
  const int hc0 = blockIdx.x * 2;

  float m = -1e30f;
  for (int t = ts * 64; t < ts * 64 + 64; ++t)
    m = fmaxf(m, scores[(size_t)t * BATCH + b]);
  red[ts][0][b] = m;
  __syncthreads();
  if (tid < 64) {
    float mm = red[0][0][b];
#pragma unroll
    for (int i = 1; i < 8; ++i) mm = fmaxf(mm, red[i][0][b]);
    mz[0][b] = mm;
  }
  __syncthreads();
  m = mz[0][b];
  float z = 0.f;
  for (int t = ts * 64; t < ts * 64 + 64; ++t)
    z += expf(scores[(size_t)t * BATCH + b] - m);
  red[ts][1][b] = z;
  __syncthreads();
  if (tid < 64) {
    float zz = 0.f;
#pragma unroll
    for (int i = 0; i < 8; ++i) zz += red[i][1][b];
    mz[1][b] = 1.f / zz;
  }
  __syncthreads();
  const float rZ = mz[1][b];

  float a0 = 0.f, a1 = 0.f;
  const float* eb = enc + HB + (size_t)hc0 * BATCH + b;
  for (int t = ts * 64; t < ts * 64 + 64; ++t) {
    float p = expf(scores[(size_t)t * BATCH + b] - m) * rZ;
    a0 += p * eb[(size_t)t * HB];
    a1 += p * eb[(size_t)t * HB + BATCH];
  }
  __syncthreads();
  red[ts][0][b] = a0;
  red[ts][1][b] = a1;
  __syncthreads();
  if (tid < 128) {
    int cl = tid >> 6;
    float c = 0.f;
#pragma unroll
    for (int i = 0; i < 8; ++i) c += red[i][cl][b];
    ctxv[cl][b] = c;
  }

  float p0 = 0.f, p1 = 0.f;
  if (s >= 1) {
    const float* w0 = w_fc + (size_t)hc0 * HDIM + ts * 64;
    const float* w1 = w0 + HDIM;
    const float* hr = h_cur + ts * 64 * BATCH;
#pragma unroll 2
    for (int k = 0; k < 64; k += 4) {
      float4 wa = ld4(w0 + k), wb = ld4(w1 + k);
      float h0 = hr[(k + 0) * BATCH + b], h1 = hr[(k + 1) * BATCH + b];
      float h2 = hr[(k + 2) * BATCH + b], h3 = hr[(k + 3) * BATCH + b];
      p0 += wa.x * h0 + wa.y * h1 + wa.z * h2 + wa.w * h3;
      p1 += wb.x * h0 + wb.y * h1 + wb.z * h2 + wb.w * h3;
    }
  }
  __syncthreads();
  red[ts][0][b] = p0;
  red[ts][1][b] = p1;
  __syncthreads();
  if (tid < 128) {
    int cl = tid >> 6;
    int cc = hc0 + cl;
    float pred = 0.f;
    if (s >= 1) {
#pragma unroll
      for (int i = 0; i < 8; ++i) pred += red[i][cl][b];
      pred += b_fc[cc];
      out[((size_t)b * NAHEAD + (s - 1)) * HDIM + cc] = pred;
    }
    xi[(size_t)cc * BATCH + b] = ctxv[cl][b] + pred;
  }
}

// ---------------------------------------------------------------------------
__global__ __launch_bounds__(512, 2)
void fc_out(const float* __restrict__ h, const float* __restrict__ w_fc,
            const float* __restrict__ b_fc, float* __restrict__ out, int srow)
{
  __shared__ float red[8][2][64];
  const int tid = threadIdx.x;
  const int b  = tid & 63;
  const int ks = tid >> 6;
  const int cc0 = blockIdx.x * 2;
  const float* w0 = w_fc + (size_t)cc0 * HDIM + ks * 64;
  const float* w1 = w0 + HDIM;
  const float* hr = h + ks * 64 * BATCH;
  float p0 = 0.f, p1 = 0.f;
#pragma unroll 2
  for (int k = 0; k < 64; k += 4) {
    float4 wa = ld4(w0 + k), wb = ld4(w1 + k);
    float h0 = hr[(k + 0) * BATCH + b], h1 = hr[(k + 1) * BATCH + b];
    float h2 = hr[(k + 2) * BATCH + b], h3 = hr[(k + 3) * BATCH + b];
    p0 += wa.x * h0 + wa.y * h1 + wa.z * h2 + wa.w * h3;
    p1 += wb.x * h0 + wb.y * h1 + wb.z * h2 + wb.w * h3;
  }
  red[ks][0][b] = p0;
  red[ks][1][b] = p1;
  __syncthreads();
  if (tid < 128) {
    int cl = tid >> 6;
    int cc = cc0 + cl;
    float p = 0.f;
#pragma unroll
    for (int i = 0; i < 8; ++i) p += red[i][cl][b];
    out[((size_t)b * NAHEAD + srow) * HDIM + cc] = p + b_fc[cc];
  }
}

// ---------------------------------------------------------------------------
__global__ __launch_bounds__(256)
void transpose_x(const float* __restrict__ x, float* __restrict__ xT)
{
  __shared__ float tile[64][65];
  const int t = blockIdx.x;
  const int lane = threadIdx.x & 63;
  const int w    = threadIdx.x >> 6;
#pragma unroll
  for (int ii = 0; ii < 16; ++ii) {
    int b = w * 16 + ii;
    tile[b][lane] = x[((size_t)b * TT + t) * IDIM + lane];
  }
  __syncthreads();
#pragma unroll
  for (int ii = 0; ii < 16; ++ii) {
    int i = w * 16 + ii;
    xT[((size_t)t * IDIM + i) * BATCH + lane] = tile[lane][i];
  }
}

// ---------------------------------------------------------------------------
extern "C" void kernel_launch(void* const* d_in, const int* in_sizes, int n_in,
                              void* d_out, int out_size, void* d_ws, size_t ws_size,
                              hipStream_t stream) {
  const float* x     = (const float*)d_in[0];
  const float* w_ih0 = (const float*)d_in[1];
  const float* w_hh0 = (const float*)d_in[2];
  const float* b_ih0 = (const float*)d_in[3];
  const float* b_hh0 = (const float*)d_in[4];
  const float* w_ih1 = (const float*)d_in[5];
  const float* w_hh1 = (const float*)d_in[6];
  const float* b_ih1 = (const float*)d_in[7];
  const float* b_hh1 = (const float*)d_in[8];
  const float* w_ihd = (const float*)d_in[9];
  const float* w_hhd = (const float*)d_in[10];
  const float* b_ihd = (const float*)d_in[11];
  const float* b_hhd = (const float*)d_in[12];
  const float* w_fc  = (const float*)d_in[13];
  const float* b_fc  = (const float*)d_in[14];
  float* out = (float*)d_out;

  char* ws = (char*)d_ws;
  size_t off = 0;
  auto alloc = [&](size_t bytes) -> void* {
    void* p = ws + off;
    off += (bytes + 255) & ~(size_t)255;
    return p;
  };

  float* cst0 = (float*)alloc((size_t)HB * 4);            // zero (fallback)
  float* cst1 = (float*)alloc((size_t)HB * 4);            // final L1 c-state
  float* seq0 = (float*)alloc((size_t)(TT + 1) * HB * 4); // slot0 zero
  float* enc  = (float*)alloc((size_t)(TT + 1) * HB * 4); // slot0 zero
  float* xT   = (float*)alloc((size_t)TT * IDIM * BATCH * 4);
  float* scores = (float*)alloc((size_t)TT * BATCH * 4);
  float* xi     = (float*)alloc((size_t)HB * 4);
  float* hdec   = (float*)alloc((size_t)2 * HB * 4);
  unsigned* bar = (unsigned*)alloc(256);                  // barrier counter
  (void)ws_size; (void)in_sizes; (void)n_in; (void)out_size;

  hipMemsetAsync(cst0, 0, (size_t)HB * 4 * 2, stream);    // cst0+cst1
  hipMemsetAsync(seq0, 0, (size_t)HB * 4, stream);
  hipMemsetAsync(enc,  0, (size_t)HB * 4, stream);
  hipMemsetAsync(bar,  0, 256, stream);

  transpose_x<<<TT, 256, 0, stream>>>(x, xT);

  // ---- encoder: ONE cooperative kernel, flush-free barrier per step ----
  static bool attr_set = false;
  if (!attr_set) {
    hipFuncSetAttribute(reinterpret_cast<const void*>(encoder_coop),
                        hipFuncAttributeMaxDynamicSharedMemorySize,
                        ENC_SMEM_BYTES);
    attr_set = true;
  }
  void* args[] = {
    (void*)&xT,
    (void*)&w_ih0, (void*)&w_hh0, (void*)&b_ih0, (void*)&b_hh0,
    (void*)&w_ih1, (void*)&w_hh1, (void*)&b_ih1, (void*)&b_hh1,
    (void*)&seq0, (void*)&enc, (void*)&cst1, (void*)&bar
  };
  hipError_t cerr = hipLaunchCooperativeKernel(
      reinterpret_cast<void*>(encoder_coop), dim3(256), dim3(1024),
      args, (unsigned)ENC_SMEM_BYTES, stream);
  if (cerr != hipSuccess) {
    // fallback: original 513 pipelined launches
    for (int t = 0; t <= TT; ++t) {
      lstm_step<<<256, 1024, 0, stream>>>(
          t, xT, w_ih0, w_hh0, b_ih0, b_hh0,
          w_ih1, w_hh1, b_ih1, b_hh1, seq0, enc, cst0, cst1);
    }
  }

  // ---- decoder (unchanged) ----
  const float* h_cur = enc + (size_t)TT * HB;
  for (int s = 0; s < NAHEAD; ++s) {
    attn_scores<<<256, 512, 0, stream>>>(enc, h_cur, scores);
    attn_ctx<<<256, 512, 0, stream>>>(enc, scores, h_cur, w_fc, b_fc,
                                      xi, out, s);
    float* h_nxt = hdec + (size_t)(s & 1) * HB;
    dec_gates<<<256, 1024, 0, stream>>>(xi, h_cur, w_ihd, w_hhd,
                                        b_ihd, b_hhd, cst1, h_nxt);
    h_cur = h_nxt;
  }
  fc_out<<<256, 512, 0, stream>>>(h_cur, w_fc, b_fc, out, NAHEAD - 1);
}

// Round 3
// 9393.208 us; speedup vs baseline: 2.3452x; 1.0868x over previous
//
#include <hip/hip_runtime.h>

#define BATCH  64
#define TT     512
#define IDIM   64
#define HDIM   512
#define NAHEAD 24
#define HB     (HDIM * BATCH)

// ---- encoder_coop LDS layout (float offsets into extern smem[]) ----
#define WIH0_OFF   0
#define WHH0_OFF   512                          // 8*64
#define WIH1_OFF   4608                         // +8*512
#define WHH1_OFF   8704
#define SCR_OFF    12800                        // scratch 8*64*17 + 8*64
#define GL_OFF     (SCR_OFF + 8 * 64 * 17)
#define BIAS0_OFF  22016                        // SCR_OFF + 9216
#define BIAS1_OFF  22024
#define ENC_SMEM_FLOATS 22048
#define ENC_SMEM_BYTES  (ENC_SMEM_FLOATS * 4)   // 88192 B < 160 KiB

__device__ __forceinline__ float4 ld4(const float* p) {
  return *reinterpret_cast<const float4*>(p);
}
__device__ __forceinline__ float sigm(float x) { return 1.0f / (1.0f + expf(-x)); }

// ---------------------------------------------------------------------------
// Flag-array grid barrier (flush-free, RMW-free arrivals).
// Arrival: each WG stores epoch to its own 64B-strided flag slot (no
// contention). Detection: WG0's wave-0 scans all 256 flags (4 loads/lane,
// 64 lanes) and publishes a single release word; all WGs poll only release.
// No cache maintenance (cg::grid.sync's L2 flush was the round-1 regression).
// Safe: every cross-WG datum is written once (agent-scope store), drained
// via vmcnt(0) before the flag store, and read only next epoch.
// ---------------------------------------------------------------------------
__device__ __forceinline__ void flag_barrier(unsigned* flags, unsigned* release,
                                             unsigned epoch, int bid) {
  asm volatile("s_waitcnt vmcnt(0)" ::: "memory");
  __syncthreads();
  if (threadIdx.x == 0)
    __hip_atomic_store(&flags[(size_t)bid * 16], epoch,
                       __ATOMIC_RELAXED, __HIP_MEMORY_SCOPE_AGENT);
  asm volatile("" ::: "memory");
  if (bid == 0 && threadIdx.x < 64) {
    const int l = threadIdx.x;
    for (;;) {
      bool ok = true;
#pragma unroll
      for (int i = 0; i < 4; ++i) {
        unsigned v = __hip_atomic_load(&flags[(size_t)(l * 4 + i) * 16],
                                       __ATOMIC_RELAXED, __HIP_MEMORY_SCOPE_AGENT);
        ok &= (v >= epoch);
      }
      if (__all(ok)) break;
      __builtin_amdgcn_s_sleep(1);
    }
    if (threadIdx.x == 0)
      __hip_atomic_store(release, epoch, __ATOMIC_RELAXED,
                         __HIP_MEMORY_SCOPE_AGENT);
  }
  if (threadIdx.x == 0) {
    while (__hip_atomic_load(release, __ATOMIC_RELAXED,
                             __HIP_MEMORY_SCOPE_AGENT) < epoch)
      __builtin_amdgcn_s_sleep(1);
  }
  __syncthreads();
  asm volatile("" ::: "memory");
}

// ---------------------------------------------------------------------------
// Persistent-weight LSTM cell. Weights/bias/scratch are INTEGER OFFSETS into
// the extern __shared__ array — guarantees addrspace(3) ds_read_b128 for the
// wave-uniform weight reads (a generic float* param risks flat_load: 64-bit
// per-lane VALU addressing + slow flat-to-LDS path => the round-2 VALUBusy).
// c-state in registers of threads tid<128; h-stores agent-scope.
// ---------------------------------------------------------------------------
template <int DIN0>
__device__ __forceinline__ void cell_lds(
    int j0,
    const float* __restrict__ in0,             // [DIN0][B] global
    const float* __restrict__ h_in,            // [512][B] global
    int wiOff, int whOff, int biasOff,         // LDS float offsets
    float& creg,
    float* __restrict__ h_out)                 // [512][B] global
{
  extern __shared__ float smem[];
  const int tid = threadIdx.x;
  const int b  = tid & 63;
  const int ks = tid >> 6;                 // 0..15, uniform per wave
  constexpr int K  = DIN0 + HDIM;
  constexpr int KS = K / 16;               // 36 (L0) / 64 (L1), %4 == 0
  const int k0 = ks * KS, k1 = k0 + KS;
  const int a0 = (k0 < DIN0) ? k0 : DIN0;
  const int a1 = (k1 < DIN0) ? k1 : DIN0;
  const int c0 = (k0 > DIN0) ? k0 - DIN0 : 0;
  const int c1 = (k1 > DIN0) ? k1 - DIN0 : 0;

  float acc[8] = {0.f, 0.f, 0.f, 0.f, 0.f, 0.f, 0.f, 0.f};

#pragma unroll 2
  for (int k = a0; k < a1; k += 4) {       // input-projection slice
    float x0 = in0[(k + 0) * BATCH + b];
    float x1 = in0[(k + 1) * BATCH + b];
    float x2 = in0[(k + 2) * BATCH + b];
    float x3 = in0[(k + 3) * BATCH + b];
#pragma unroll
    for (int d = 0; d < 8; ++d) {
      float4 w = ld4(&smem[wiOff + d * DIN0 + k]);  // ds_read_b128 broadcast
      acc[d] += x0 * w.x + x1 * w.y + x2 * w.z + x3 * w.w;
    }
  }
#pragma unroll 2
  for (int k = c0; k < c1; k += 4) {       // recurrent slice
    float h0 = h_in[(k + 0) * BATCH + b];
    float h1 = h_in[(k + 1) * BATCH + b];
    float h2 = h_in[(k + 2) * BATCH + b];
    float h3 = h_in[(k + 3) * BATCH + b];
#pragma unroll
    for (int d = 0; d < 8; ++d) {
      float4 w = ld4(&smem[whOff + d * HDIM + k]);
      acc[d] += h0 * w.x + h1 * w.y + h2 * w.z + h3 * w.w;
    }
  }

#pragma unroll
  for (int d = 0; d < 8; ++d) smem[SCR_OFF + (d * 64 + b) * 17 + ks] = acc[d];
  __syncthreads();

  if (tid < 512) {                          // reduce 16 partials per dot
    const int dd = tid >> 6, bb = tid & 63;
    float s = 0.f;
#pragma unroll
    for (int i = 0; i < 16; ++i) s += smem[SCR_OFF + (dd * 64 + bb) * 17 + i];
    smem[GL_OFF + dd * 64 + bb] = s + smem[biasOff + dd];
  }
  __syncthreads();

  if (tid < 128) {                          // cell update (col, b), c in reg
    const int bb = tid & 63, cl = tid >> 6;
    float gi = smem[GL_OFF + (0 + cl) * 64 + bb];   // gate order i,f,g,o
    float gf = smem[GL_OFF + (2 + cl) * 64 + bb];
    float gg = smem[GL_OFF + (4 + cl) * 64 + bb];
    float go = smem[GL_OFF + (6 + cl) * 64 + bb];
    float cn = sigm(gf) * creg + sigm(gi) * tanhf(gg);
    float hn = sigm(go) * tanhf(cn);
    creg = cn;
    __hip_atomic_store(&h_out[(size_t)(j0 + cl) * BATCH + bb], hn,
                       __ATOMIC_RELAXED, __HIP_MEMORY_SCOPE_AGENT);
  }
  __syncthreads();   // scratch safe for reuse
}

// ---------------------------------------------------------------------------
// Whole encoder in ONE cooperative kernel: 256 WGs x 1024 (1 WG/CU).
// ---------------------------------------------------------------------------
__global__ __launch_bounds__(1024, 1)
void encoder_coop(const float* __restrict__ xT,
                  const float* __restrict__ w_ih0, const float* __restrict__ w_hh0,
                  const float* __restrict__ b_ih0, const float* __restrict__ b_hh0,
                  const float* __restrict__ w_ih1, const float* __restrict__ w_hh1,
                  const float* __restrict__ b_ih1, const float* __restrict__ b_hh1,
                  float* __restrict__ seq0,        // [T+1][H][B], slot0 zero
                  float* __restrict__ enc,         // [T+1][H][B], slot0 zero
                  float* __restrict__ cst1,        // [H][B] final L1 c-state
                  unsigned* flags, unsigned* release)
{
  extern __shared__ float smem[];
  const int tid = threadIdx.x;
  const int bid = blockIdx.x;
  const int j0  = bid * 2;

  // ---- one-time weight staging: rows r(d) = (d>>1)*HDIM + j0 + (d&1) ----
  for (int idx = tid; idx < 8 * IDIM; idx += 1024) {
    int d = idx >> 6, k = idx & 63;
    size_t r = (size_t)((d >> 1) * HDIM + j0 + (d & 1));
    smem[WIH0_OFF + idx] = w_ih0[r * IDIM + k];
  }
  for (int idx = tid; idx < 8 * HDIM; idx += 1024) {
    int d = idx >> 9, k = idx & 511;
    size_t r = (size_t)((d >> 1) * HDIM + j0 + (d & 1));
    smem[WHH0_OFF + idx] = w_hh0[r * HDIM + k];
    smem[WIH1_OFF + idx] = w_ih1[r * HDIM + k];
    smem[WHH1_OFF + idx] = w_hh1[r * HDIM + k];
  }
  if (tid < 8) {
    size_t r = (size_t)((tid >> 1) * HDIM + j0 + (tid & 1));
    smem[BIAS0_OFF + tid] = b_ih0[r] + b_hh0[r];
    smem[BIAS1_OFF + tid] = b_ih1[r] + b_hh1[r];
  }
  __syncthreads();

  float c0reg = 0.f, c1reg = 0.f;              // c-state (threads tid<128)

  for (int t = 0; t <= TT; ++t) {
    if (t < TT)
      cell_lds<IDIM>(j0, xT + (size_t)t * IDIM * BATCH,
                     seq0 + (size_t)t * HB,
                     WIH0_OFF, WHH0_OFF, BIAS0_OFF, c0reg,
                     seq0 + (size_t)(t + 1) * HB);
    if (t >= 1)
      cell_lds<HDIM>(j0, seq0 + (size_t)t * HB,
                     enc + (size_t)(t - 1) * HB,
                     WIH1_OFF, WHH1_OFF, BIAS1_OFF, c1reg,
                     enc + (size_t)t * HB);
    if (t < TT) flag_barrier(flags, release, (unsigned)(t + 1), bid);
  }

  if (tid < 128)                               // decoder continues this c
    cst1[(size_t)(j0 + (tid >> 6)) * BATCH + (tid & 63)] = c1reg;
}

// ---------------------------------------------------------------------------
// Original global-weight cell (kept for dec_gates + launch fallback).
// ---------------------------------------------------------------------------
template <int DIN0>
__device__ __forceinline__ void cell_tile2(
    int j0, const float* __restrict__ in0,
    const float* __restrict__ h_in,
    const float* __restrict__ w_ih,
    const float* __restrict__ w_hh,
    const float* __restrict__ b_ih, const float* __restrict__ b_hh,
    float* __restrict__ c_state,
    float* __restrict__ h_out,
    float* __restrict__ sm)
{
  const int tid = threadIdx.x;
  const int b  = tid & 63;
  const int ks = tid >> 6;
  constexpr int K  = DIN0 + HDIM;
  constexpr int KS = K / 16;
  const int k0 = ks * KS, k1 = k0 + KS;
  const int a0 = (k0 < DIN0) ? k0 : DIN0;
  const int a1 = (k1 < DIN0) ? k1 : DIN0;
  const int c0 = (k0 > DIN0) ? k0 - DIN0 : 0;
  const int c1 = (k1 > DIN0) ? k1 - DIN0 : 0;

  const float* wi = w_ih + (size_t)j0 * DIN0;
  const float* wh = w_hh + (size_t)j0 * HDIM;

  float acc[8] = {0.f, 0.f, 0.f, 0.f, 0.f, 0.f, 0.f, 0.f};

#pragma unroll 2
  for (int k = a0; k < a1; k += 4) {
    float x0 = in0[(k + 0) * BATCH + b];
    float x1 = in0[(k + 1) * BATCH + b];
    float x2 = in0[(k + 2) * BATCH + b];
    float x3 = in0[(k + 3) * BATCH + b];
#pragma unroll
    for (int d = 0; d < 8; ++d) {
      float4 w = ld4(wi + (size_t)((d >> 1) * HDIM + (d & 1)) * DIN0 + k);
      acc[d] += x0 * w.x + x1 * w.y + x2 * w.z + x3 * w.w;
    }
  }
#pragma unroll 2
  for (int k = c0; k < c1; k += 4) {
    float h0 = h_in[(k + 0) * BATCH + b];
    float h1 = h_in[(k + 1) * BATCH + b];
    float h2 = h_in[(k + 2) * BATCH + b];
    float h3 = h_in[(k + 3) * BATCH + b];
#pragma unroll
    for (int d = 0; d < 8; ++d) {
      float4 w = ld4(wh + (size_t)((d >> 1) * HDIM + (d & 1)) * HDIM + k);
      acc[d] += h0 * w.x + h1 * w.y + h2 * w.z + h3 * w.w;
    }
  }

  float* gl = sm + 8 * 64 * 17;
#pragma unroll
  for (int d = 0; d < 8; ++d) sm[(d * 64 + b) * 17 + ks] = acc[d];
  __syncthreads();

  if (tid < 512) {
    const int dd = tid >> 6, bb = tid & 63;
    float s = 0.f;
#pragma unroll
    for (int i = 0; i < 16; ++i) s += sm[(dd * 64 + bb) * 17 + i];
    const int r = (dd >> 1) * HDIM + j0 + (dd & 1);
    gl[dd * 64 + bb] = s + b_ih[r] + b_hh[r];
  }
  __syncthreads();

  if (tid < 128) {
    const int bb = tid & 63, cl = tid >> 6;
    const int jc = j0 + cl;
    float gi = gl[(0 + cl) * 64 + bb];
    float gf = gl[(2 + cl) * 64 + bb];
    float gg = gl[(4 + cl) * 64 + bb];
    float go = gl[(6 + cl) * 64 + bb];
    float cold = c_state[(size_t)jc * BATCH + bb];
    float cn = sigm(gf) * cold + sigm(gi) * tanhf(gg);
    float hn = sigm(go) * tanhf(cn);
    c_state[(size_t)jc * BATCH + bb] = cn;
    h_out[(size_t)jc * BATCH + bb] = hn;
  }
  __syncthreads();
}

// Fallback per-step kernel (only used if cooperative launch fails).
__global__ __launch_bounds__(1024, 1)
void lstm_step(int t,
               const float* __restrict__ xT,
               const float* __restrict__ w_ih0, const float* __restrict__ w_hh0,
               const float* __restrict__ b_ih0, const float* __restrict__ b_hh0,
               const float* __restrict__ w_ih1, const float* __restrict__ w_hh1,
               const float* __restrict__ b_ih1, const float* __restrict__ b_hh1,
               float* __restrict__ seq0, float* __restrict__ enc,
               float* __restrict__ cst0, float* __restrict__ cst1)
{
  __shared__ float sm[8 * 64 * 17 + 8 * 64];
  const int j0 = blockIdx.x * 2;
  if (t < TT)
    cell_tile2<IDIM>(j0, xT + (size_t)t * IDIM * BATCH,
                     seq0 + (size_t)t * HB,
                     w_ih0, w_hh0, b_ih0, b_hh0,
                     cst0, seq0 + (size_t)(t + 1) * HB, sm);
  if (t >= 1)
    cell_tile2<HDIM>(j0, seq0 + (size_t)t * HB,
                     enc + (size_t)(t - 1) * HB,
                     w_ih1, w_hh1, b_ih1, b_hh1,
                     cst1, enc + (size_t)t * HB, sm);
}

// ---------------------------------------------------------------------------
__global__ __launch_bounds__(1024, 1)
void dec_gates(const float* __restrict__ xi, const float* __restrict__ h_cur,
               const float* __restrict__ w_ih, const float* __restrict__ w_hh,
               const float* __restrict__ b_ih, const float* __restrict__ b_hh,
               float* __restrict__ cst, float* __restrict__ h_out)
{
  __shared__ float sm[8 * 64 * 17 + 8 * 64];
  cell_tile2<HDIM>(blockIdx.x * 2, xi, h_cur, w_ih, w_hh, b_ih, b_hh,
                   cst, h_out, sm);
}

// ---------------------------------------------------------------------------
__global__ __launch_bounds__(512, 2)
void attn_scores(const float* __restrict__ enc,
                 const float* __restrict__ h_cur,
                 float* __restrict__ scores)
{
  __shared__ float red[2][8][64];
  const int tid = threadIdx.x;
  const int b  = tid & 63;
  const int ks = tid >> 6;
  const int t0 = blockIdx.x * 2;
  const float* e0 = enc + (size_t)(t0 + 1) * HB + ks * 64 * BATCH;
  const float* e1 = e0 + HB;
  const float* hr = h_cur + ks * 64 * BATCH;
  float a0 = 0.f, a1 = 0.f;
#pragma unroll 4
  for (int k = 0; k < 64; ++k) {
    float hv = hr[k * BATCH + b];
    a0 += hv * e0[k * BATCH + b];
    a1 += hv * e1[k * BATCH + b];
  }
  red[0][ks][b] = a0;
  red[1][ks][b] = a1;
  __syncthreads();
  if (tid < 128) {
    int tl = tid >> 6;
    float s = 0.f;
#pragma unroll
    for (int i = 0; i < 8; ++i) s += red[tl][i][b];
    scores[(size_t)(t0 + tl) * BATCH + b] = s;
  }
}

// ---------------------------------------------------------------------------
__global__ __launch_bounds__(512, 2)
void attn_ctx(const float* __restrict__ enc,
              const float* __restrict__ scores,
              const float* __restrict__ h_cur,
              const float* __restrict__ w_fc, const float* __restrict__ b_fc,
              float* __restrict__ xi,
              float* __restrict__ out,
              int s)
{
  __shared__ float red[8][2][64];
  __shared__ float mz[2][64];
  __shared__ float ctxv[2][64];
  const int tid = threadIdx.x;
  const int b  = tid & 63;
  const int ts = tid >> 6;
  const int hc0 = blockIdx.x * 2;

  float m = -1e30f;
  for (int t = ts * 64; t < ts * 64 + 64; ++t)
    m = fmaxf(m, scores[(size_t)t * BATCH + b]);
  red[ts][0][b] = m;
  __syncthreads();
  if (tid < 64) {
    float mm = red[0][0][b];
#pragma unroll
    for (int i = 1; i < 8; ++i) mm = fmaxf(mm, red[i][0][b]);
    mz[0][b] = mm;
  }
  __syncthreads();
  m = mz[0][b];
  float z = 0.f;
  for (int t = ts * 64; t < ts * 64 + 64; ++t)
    z += expf(scores[(size_t)t * BATCH + b] - m);
  red[ts][1][b] = z;
  __syncthreads();
  if (tid < 64) {
    float zz = 0.f;
#pragma unroll
    for (int i = 0; i < 8; ++i) zz += red[i][1][b];
    mz[1][b] = 1.f / zz;
  }
  __syncthreads();
  const float rZ = mz[1][b];

  float a0 = 0.f, a1 = 0.f;
  const float* eb = enc + HB + (size_t)hc0 * BATCH + b;
  for (int t = ts * 64; t < ts * 64 + 64; ++t) {
    float p = expf(scores[(size_t)t * BATCH + b] - m) * rZ;
    a0 += p * eb[(size_t)t * HB];
    a1 += p * eb[(size_t)t * HB + BATCH];
  }
  __syncthreads();
  red[ts][0][b] = a0;
  red[ts][1][b] = a1;
  __syncthreads();
  if (tid < 128) {
    int cl = tid >> 6;
    float c = 0.f;
#pragma unroll
    for (int i = 0; i < 8; ++i) c += red[i][cl][b];
    ctxv[cl][b] = c;
  }

  float p0 = 0.f, p1 = 0.f;
  if (s >= 1) {
    const float* w0 = w_fc + (size_t)hc0 * HDIM + ts * 64;
    const float* w1 = w0 + HDIM;
    const float* hr = h_cur + ts * 64 * BATCH;
#pragma unroll 2
    for (int k = 0; k < 64; k += 4) {
      float4 wa = ld4(w0 + k), wb = ld4(w1 + k);
      float h0 = hr[(k + 0) * BATCH + b], h1 = hr[(k + 1) * BATCH + b];
      float h2 = hr[(k + 2) * BATCH + b], h3 = hr[(k + 3) * BATCH + b];
      p0 += wa.x * h0 + wa.y * h1 + wa.z * h2 + wa.w * h3;
      p1 += wb.x * h0 + wb.y * h1 + wb.z * h2 + wb.w * h3;
    }
  }
  __syncthreads();
  red[ts][0][b] = p0;
  red[ts][1][b] = p1;
  __syncthreads();
  if (tid < 128) {
    int cl = tid >> 6;
    int cc = hc0 + cl;
    float pred = 0.f;
    if (s >= 1) {
#pragma unroll
      for (int i = 0; i < 8; ++i) pred += red[i][cl][b];
      pred += b_fc[cc];
      out[((size_t)b * NAHEAD + (s - 1)) * HDIM + cc] = pred;
    }
    xi[(size_t)cc * BATCH + b] = ctxv[cl][b] + pred;
  }
}

// ---------------------------------------------------------------------------
__global__ __launch_bounds__(512, 2)
void fc_out(const float* __restrict__ h, const float* __restrict__ w_fc,
            const float* __restrict__ b_fc, float* __restrict__ out, int srow)
{
  __shared__ float red[8][2][64];
  const int tid = threadIdx.x;
  const int b  = tid & 63;
  const int ks = tid >> 6;
  const int cc0 = blockIdx.x * 2;
  const float* w0 = w_fc + (size_t)cc0 * HDIM + ks * 64;
  const float* w1 = w0 + HDIM;
  const float* hr = h + ks * 64 * BATCH;
  float p0 = 0.f, p1 = 0.f;
#pragma unroll 2
  for (int k = 0; k < 64; k += 4) {
    float4 wa = ld4(w0 + k), wb = ld4(w1 + k);
    float h0 = hr[(k + 0) * BATCH + b], h1 = hr[(k + 1) * BATCH + b];
    float h2 = hr[(k + 2) * BATCH + b], h3 = hr[(k + 3) * BATCH + b];
    p0 += wa.x * h0 + wa.y * h1 + wa.z * h2 + wa.w * h3;
    p1 += wb.x * h0 + wb.y * h1 + wb.z * h2 + wb.w * h3;
  }
  red[ks][0][b] = p0;
  red[ks][1][b] = p1;
  __syncthreads();
  if (tid < 128) {
    int cl = tid >> 6;
    int cc = cc0 + cl;
    float p = 0.f;
#pragma unroll
    for (int i = 0; i < 8; ++i) p += red[i][cl][b];
    out[((size_t)b * NAHEAD + srow) * HDIM + cc] = p + b_fc[cc];
  }
}

// ---------------------------------------------------------------------------
__global__ __launch_bounds__(256)
void transpose_x(const float* __restrict__ x, float* __restrict__ xT)
{
  __shared__ float tile[64][65];
  const int t = blockIdx.x;
  const int lane = threadIdx.x & 63;
  const int w    = threadIdx.x >> 6;
#pragma unroll
  for (int ii = 0; ii < 16; ++ii) {
    int b = w * 16 + ii;
    tile[b][lane] = x[((size_t)b * TT + t) * IDIM + lane];
  }
  __syncthreads();
#pragma unroll
  for (int ii = 0; ii < 16; ++ii) {
    int i = w * 16 + ii;
    xT[((size_t)t * IDIM + i) * BATCH + lane] = tile[lane][i];
  }
}

// ---------------------------------------------------------------------------
extern "C" void kernel_launch(void* const* d_in, const int* in_sizes, int n_in,
                              void* d_out, int out_size, void* d_ws, size_t ws_size,
                              hipStream_t stream) {
  const float* x     = (const float*)d_in[0];
  const float* w_ih0 = (const float*)d_in[1];
  const float* w_hh0 = (const float*)d_in[2];
  const float* b_ih0 = (const float*)d_in[3];
  const float* b_hh0 = (const float*)d_in[4];
  const float* w_ih1 = (const float*)d_in[5];
  const float* w_hh1 = (const float*)d_in[6];
  const float* b_ih1 = (const float*)d_in[7];
  const float* b_hh1 = (const float*)d_in[8];
  const float* w_ihd = (const float*)d_in[9];
  const float* w_hhd = (const float*)d_in[10];
  const float* b_ihd = (const float*)d_in[11];
  const float* b_hhd = (const float*)d_in[12];
  const float* w_fc  = (const float*)d_in[13];
  const float* b_fc  = (const float*)d_in[14];
  float* out = (float*)d_out;

  char* ws = (char*)d_ws;
  size_t off = 0;
  auto alloc = [&](size_t bytes) -> void* {
    void* p = ws + off;
    off += (bytes + 255) & ~(size_t)255;
    return p;
  };

  float* cst0 = (float*)alloc((size_t)HB * 4);            // zero (fallback)
  float* cst1 = (float*)alloc((size_t)HB * 4);            // final L1 c-state
  float* seq0 = (float*)alloc((size_t)(TT + 1) * HB * 4); // slot0 zero
  float* enc  = (float*)alloc((size_t)(TT + 1) * HB * 4); // slot0 zero
  float* xT   = (float*)alloc((size_t)TT * IDIM * BATCH * 4);
  float* scores = (float*)alloc((size_t)TT * BATCH * 4);
  float* xi     = (float*)alloc((size_t)HB * 4);
  float* hdec   = (float*)alloc((size_t)2 * HB * 4);
  unsigned* flags   = (unsigned*)alloc(256 * 16 * 4);     // 64B-strided flags
  unsigned* release = (unsigned*)alloc(256);
  (void)ws_size; (void)in_sizes; (void)n_in; (void)out_size;

  hipMemsetAsync(cst0, 0, (size_t)HB * 4 * 2, stream);    // cst0+cst1
  hipMemsetAsync(seq0, 0, (size_t)HB * 4, stream);
  hipMemsetAsync(enc,  0, (size_t)HB * 4, stream);
  hipMemsetAsync(flags, 0, 256 * 16 * 4, stream);
  hipMemsetAsync(release, 0, 256, stream);

  transpose_x<<<TT, 256, 0, stream>>>(x, xT);

  // ---- encoder: ONE cooperative kernel, flag barrier per step ----
  static bool attr_set = false;
  if (!attr_set) {
    hipFuncSetAttribute(reinterpret_cast<const void*>(encoder_coop),
                        hipFuncAttributeMaxDynamicSharedMemorySize,
                        ENC_SMEM_BYTES);
    attr_set = true;
  }
  void* args[] = {
    (void*)&xT,
    (void*)&w_ih0, (void*)&w_hh0, (void*)&b_ih0, (void*)&b_hh0,
    (void*)&w_ih1, (void*)&w_hh1, (void*)&b_ih1, (void*)&b_hh1,
    (void*)&seq0, (void*)&enc, (void*)&cst1, (void*)&flags, (void*)&release
  };
  hipError_t cerr = hipLaunchCooperativeKernel(
      reinterpret_cast<void*>(encoder_coop), dim3(256), dim3(1024),
      args, (unsigned)ENC_SMEM_BYTES, stream);
  if (cerr != hipSuccess) {
    // fallback: original 513 pipelined launches
    for (int t = 0; t <= TT; ++t) {
      lstm_step<<<256, 1024, 0, stream>>>(
          t, xT, w_ih0, w_hh0, b_ih0, b_hh0,
          w_ih1, w_hh1, b_ih1, b_hh1, seq0, enc, cst0, cst1);
    }
  }

  // ---- decoder (unchanged) ----
  const float* h_cur = enc + (size_t)TT * HB;
  for (int s = 0; s < NAHEAD; ++s) {
    attn_scores<<<256, 512, 0, stream>>>(enc, h_cur, scores);
    attn_ctx<<<256, 512, 0, stream>>>(enc, scores, h_cur, w_fc, b_fc,
                                      xi, out, s);
    float* h_nxt = hdec + (size_t)(s & 1) * HB;
    dec_gates<<<256, 1024, 0, stream>>>(xi, h_cur, w_ihd, w_hhd,
                                        b_ihd, b_hhd, cst1, h_nxt);
    h_cur = h_nxt;
  }
  fc_out<<<256, 512, 0, stream>>>(h_cur, w_fc, b_fc, out, NAHEAD - 1);
}